// Round 1
// baseline (177.940 us; speedup 1.0000x reference)
//
#include <hip/hip_runtime.h>

#define MTOT 16384        // 8*2048 tokens
#define NFEAT 512         // out features
#define KTOT 4608         // 512 inputs * 9 segments

typedef float f32x4 __attribute__((ext_vector_type(4)));
typedef short s16x8 __attribute__((ext_vector_type(8)));

__device__ __forceinline__ int div9(int c) { return (c * 7282) >> 16; }  // exact for 0 <= c < 32768

#define GLDS(GP, LP) __builtin_amdgcn_global_load_lds( \
    (const __attribute__((address_space(1))) void*)(GP), \
    (__attribute__((address_space(3))) void*)(LP), 16, 0, 0)

// branchless decode: one code byte -> 8 bf16 one-hot fragment
__device__ __forceinline__ s16x8 decode_frag(unsigned code) {
  unsigned nb0 = code & 15u, nb1 = code >> 4;
  unsigned p0 = nb0 - 1u, p1 = nb1 - 1u;  // wraps to 0xFFFFFFFF when nb==0
  unsigned long long v0 = (nb0 ? 0x3F80ull : 0ull) << ((p0 & 3u) << 4);
  unsigned long long v1 = (nb1 ? 0x3F80ull : 0ull) << ((p1 & 3u) << 4);
  unsigned long long lo = (p0 < 4u ? v0 : 0ull) | (p1 < 4u ? v1 : 0ull);
  unsigned long long hi = (p0 < 4u ? 0ull : v0) | (p1 < 4u ? 0ull : v1);
  union { unsigned long long q[2]; s16x8 v; } u;
  u.q[0] = lo; u.q[1] = hi;
  return u.v;
}

// ---------------- fused prep: bx<2048 -> build_b, else build_codes ----------------
__global__ __launch_bounds__(256) void prep(const float* __restrict__ x,
                                            const float* __restrict__ coeffs,
                                            unsigned char* __restrict__ codeT,
                                            unsigned short* __restrict__ Bmat) {
  __shared__ unsigned char segt[64][68];
  const int bx = blockIdx.x;
  const int tid = threadIdx.x;
  if (bx < 2048) {
    // ---- build_b: coeffs -> Bmat[i][k] bf16, k = j*9+s ----
    const int i = bx >> 2, q = bx & 3;
    const float* cb = coeffs + (size_t)i * 6144;
#pragma unroll
    for (int p = 0; p < 5; ++p) {
      int kl = p * 256 + tid;
      if (kl < 1152) {
        int k = q * 1152 + kl;
        int j = div9(k), s = k - j * 9;
        float v = cb[j * 12 + s] + cb[j * 12 + s + 1] + cb[j * 12 + s + 2];
        unsigned u = __float_as_uint(v);
        unsigned rn = (u + 0x7FFFu + ((u >> 16) & 1u)) >> 16;  // RNE f32->bf16
        Bmat[(size_t)i * KTOT + k] = (unsigned short)rn;
      }
    }
  } else {
    // ---- build_codes: x -> codeT[g][m], 64 tokens x 64 inputs per block ----
    const int bb = bx - 2048;
    const int mt = bb >> 3;   // 0..255
    const int jt = bb & 7;    // 0..7
    const int m0 = mt * 64;
    const float4* x4 = (const float4*)x;
    const float T1 = (float)(1.0/9.0), T2 = (float)(2.0/9.0), T3 = (float)(3.0/9.0),
                T4 = (float)(4.0/9.0), T5 = (float)(5.0/9.0), T6 = (float)(6.0/9.0),
                T7 = (float)(7.0/9.0), T8 = (float)(8.0/9.0);
#pragma unroll
    for (int it = 0; it < 4; ++it) {
      int f = it * 256 + tid;
      int m = f >> 4, jq = f & 15;
      float4 v = x4[(size_t)(m0 + m) * 128 + jt * 16 + jq];
      uchar4 sv;
      { float xv = v.x; sv.x = (unsigned char)((xv>=T1)+(xv>=T2)+(xv>=T3)+(xv>=T4)+(xv>=T5)+(xv>=T6)+(xv>=T7)+(xv>=T8)); }
      { float xv = v.y; sv.y = (unsigned char)((xv>=T1)+(xv>=T2)+(xv>=T3)+(xv>=T4)+(xv>=T5)+(xv>=T6)+(xv>=T7)+(xv>=T8)); }
      { float xv = v.z; sv.z = (unsigned char)((xv>=T1)+(xv>=T2)+(xv>=T3)+(xv>=T4)+(xv>=T5)+(xv>=T6)+(xv>=T7)+(xv>=T8)); }
      { float xv = v.w; sv.w = (unsigned char)((xv>=T1)+(xv>=T2)+(xv>=T3)+(xv>=T4)+(xv>=T5)+(xv>=T6)+(xv>=T7)+(xv>=T8)); }
      *(uchar4*)&segt[m][jq * 4] = sv;
    }
    __syncthreads();
#pragma unroll
    for (int p = 0; p < 5; ++p) {
      int u = p * 256 + tid;
      if (u < 1152) {
        int gl = u >> 4, mq = u & 15;
        int c0 = jt * 576 + gl * 8;
        int j0 = div9(c0), j1 = div9(c0 + 7);
        int j0l = j0 - jt * 64, j1l = j1 - jt * 64;
        uchar4 ob;
        unsigned char* pb = (unsigned char*)&ob;
#pragma unroll
        for (int c = 0; c < 4; ++c) {
          int m = mq * 4 + c;
          int s0 = segt[m][j0l];
          int pos0 = j0 * 9 + s0 - c0;
          unsigned code = (pos0 >= 0 && pos0 < 8) ? (unsigned)(pos0 + 1) : 0u;
          if (j1 != j0) {
            int s1 = segt[m][j1l];
            int pos1 = j1 * 9 + s1 - c0;
            if (pos1 < 8) code |= (unsigned)(pos1 + 1) << 4;
          }
          pb[c] = (unsigned char)code;
        }
        *(uchar4*)(codeT + (size_t)(jt * 72 + gl) * MTOT + m0 + mq * 4) = ob;
      }
    }
  }
}

// ---------------- main: one-hot bf16 MFMA GEMM, counted-vmcnt 4-deep pipeline ----------------
// Structure (T3+T4+T5 port): one raw s_barrier per K-tile, s_waitcnt vmcnt(16)
// (= "everything >=3 iterations old complete"; each iteration issues exactly
// 8 VMEM ops: 4 code ubyte loads + 4 global_load_lds), 4-deep LDS B-buffer,
// codes prefetched 4 tiles ahead into 4 named register sets, setprio around MFMA.
__global__ __launch_bounds__(256, 2) void kan_gemm(const unsigned char* __restrict__ codeT,
                                                   const unsigned short* __restrict__ Bmat,
                                                   float* __restrict__ out) {
  __shared__ __align__(16) short Blds[4][16 * 512];  // 4 x 16KB, fragment-major
  const int tid = threadIdx.x;
  const int lane = tid & 63;
  const int wid = tid >> 6;
  const int lm = lane & 15;
  const int lq = lane >> 4;
  const int bx = blockIdx.x;
  const int rr8 = bx & 7, qq = bx >> 3;
  const int nt = rr8 & 3;
  const int mt = qq * 2 + (rr8 >> 2);
  const int m0 = mt * 128, n0 = nt * 128;
  const int wr = wid;  // wave owns m-rows [wr*32, wr*32+32), all 128 n-cols

  // B staging pointers (per-wave slots pp = wid*4 + {0..3})
  const unsigned short* gB0 = Bmat + (size_t)(n0 + (wid * 2 + 0) * 16 + lm) * KTOT + lq * 8;
  const unsigned short* gB1 = Bmat + (size_t)(n0 + (wid * 2 + 1) * 16 + lm) * KTOT + lq * 8;
  // code pointers: frag f = ms*2+ks; addr = (ks*4+lq)*MTOT + m0 + wr*32 + ms*16 + lm
  const unsigned char* gC0 = codeT + (size_t)lq * MTOT + m0 + wr * 32 + lm;        // ks=0
  const unsigned char* gC1 = codeT + (size_t)(4 + lq) * MTOT + m0 + wr * 32 + lm;  // ks=1

  f32x4 acc[2][8] = {};
  s16x8 afX[4], afY[4];
  unsigned char crQ[4][4];  // 4 in-flight code sets (constant-indexed -> registers)

#define CRLOAD(SET) do { \
    crQ[SET][0] = gC0[0]; crQ[SET][1] = gC1[0]; \
    crQ[SET][2] = gC0[16]; crQ[SET][3] = gC1[16]; \
    gC0 += (size_t)8 * MTOT; gC1 += (size_t)8 * MTOT; } while (0)

#define ISSUE_B(SLOT) do { \
    short* base = &Blds[SLOT][0] + wid * 2048; \
    GLDS(gB0,      base);        \
    GLDS(gB0 + 32, base + 512);  \
    GLDS(gB1,      base + 1024); \
    GLDS(gB1 + 32, base + 1536); \
    gB0 += 64; gB1 += 64; } while (0)

#define DECODE(SET, AF) do { \
    _Pragma("unroll") \
    for (int f = 0; f < 4; ++f) AF[f] = decode_frag(crQ[SET][f]); } while (0)

#define COMPUTE(AF, SLOT) do { \
    __builtin_amdgcn_s_setprio(1); \
    _Pragma("unroll") \
    for (int ks = 0; ks < 2; ++ks) { \
      s16x8 bf[8]; \
      _Pragma("unroll") \
      for (int ns = 0; ns < 8; ++ns) \
        bf[ns] = *(const s16x8*)&Blds[SLOT][(ns * 2 + ks) * 512 + lane * 8]; \
      _Pragma("unroll") \
      for (int ms = 0; ms < 2; ++ms) \
        _Pragma("unroll") \
        for (int ns = 0; ns < 8; ++ns) \
          acc[ms][ns] = __builtin_amdgcn_mfma_f32_16x16x32_bf16(AF[ms * 2 + ks], bf[ns], acc[ms][ns], 0, 0, 0); \
    } \
    __builtin_amdgcn_s_setprio(0); } while (0)

#define VWAIT(N) asm volatile("s_waitcnt vmcnt(" #N ")" ::: "memory")
#define FENCE()  asm volatile("" ::: "memory")
#define BAR()    __builtin_amdgcn_s_barrier()

  // ---- prologue: codes for tiles 0..3, B for tiles 0..2 (fenced so issue
  // order is iteration-granular; vmcnt counts below rely on that) ----
  CRLOAD(0); FENCE();
  CRLOAD(1); ISSUE_B(0); FENCE();
  CRLOAD(2); ISSUE_B(1); FENCE();
  CRLOAD(3); ISSUE_B(2); FENCE();
  VWAIT(24);            // CR(0) complete (3 iteration-groups = 24 ops newer)
  DECODE(0, afX);       // frags for tile 0

  // ---- main loop: 17 groups x 4 tiles (t = 4k+p), tiles 0..67 ----
  // per position: vmcnt(16) => B(t) and CR(t+1) complete (both live in the
  // iteration 3 back; 2 full iterations = 16 ops stay in flight), barrier,
  // then issue CR(t+4)/B(t+3) and compute tile t.
#pragma unroll 1
  for (int k = 0; k < 17; ++k) {
    VWAIT(16); BAR();
    CRLOAD(0); ISSUE_B(3);       // CR(t+4)->crQ[0], B(t+3)->slot3   (t=4k)
    DECODE(1, afY);              // tile t+1
    COMPUTE(afX, 0);

    VWAIT(16); BAR();
    CRLOAD(1); ISSUE_B(0);
    DECODE(2, afX);
    COMPUTE(afY, 1);

    VWAIT(16); BAR();
    CRLOAD(2); ISSUE_B(1);
    DECODE(3, afY);
    COMPUTE(afX, 2);

    VWAIT(16); BAR();
    CRLOAD(3); ISSUE_B(2);
    DECODE(0, afX);              // tile 4k+4 (loaded this group at p0)
    COMPUTE(afY, 3);
  }

  // ---- tail: tiles 68..71 (codes 69..71 already in crQ[1..3]) ----
  VWAIT(16); BAR();
  ISSUE_B(3);                    // B(71) -> slot 3
  DECODE(1, afY);                // tile 69
  COMPUTE(afX, 0);               // tile 68

  VWAIT(12); BAR();              // forces B(69), CR(70)
  DECODE(2, afX);                // tile 70
  COMPUTE(afY, 1);               // tile 69

  VWAIT(4); BAR();               // forces B(70), CR(71)
  DECODE(3, afY);                // tile 71
  COMPUTE(afX, 2);               // tile 70

  VWAIT(0); BAR();               // forces B(71)
  COMPUTE(afY, 3);               // tile 71

  // epilogue: C/D layout col=lane&15, row=quad*4+reg (verified R1/R2)
#pragma unroll
  for (int ms = 0; ms < 2; ++ms) {
#pragma unroll
    for (int ns = 0; ns < 8; ++ns) {
      int tok = m0 + wr * 32 + ms * 16 + lq * 4;
      int col = n0 + ns * 16 + lm;
      float* op = out + (size_t)tok * NFEAT + col;
#pragma unroll
      for (int rg = 0; rg < 4; ++rg) op[(size_t)rg * NFEAT] = acc[ms][ns][rg];
    }
  }
#undef CRLOAD
#undef ISSUE_B
#undef DECODE
#undef COMPUTE
#undef VWAIT
#undef FENCE
#undef BAR
}

extern "C" void kernel_launch(void* const* d_in, const int* in_sizes, int n_in,
                              void* d_out, int out_size, void* d_ws, size_t ws_size,
                              hipStream_t stream) {
  const float* x = (const float*)d_in[0];        // [16384, 512] f32
  const float* coeffs = (const float*)d_in[1];   // [512, 512, 12] f32
  float* out = (float*)d_out;                    // [16384, 512] f32
  unsigned char* codeT = (unsigned char*)d_ws;                                  // 576*16384 = 9.44 MB
  unsigned short* Bmat = (unsigned short*)((char*)d_ws + (size_t)576 * MTOT);   // 512*4608*2 = 4.72 MB

  prep<<<dim3(4096), dim3(256), 0, stream>>>(x, coeffs, codeT, Bmat);
  kan_gemm<<<dim3(512), dim3(256), 0, stream>>>(codeT, Bmat, out);
}